// Round 7
// baseline (25.859 us; speedup 1.0000x reference)
//
#include <hip/hip_runtime.h>

// PyBlaz 8x8 block DCT + int8 quantization, one thread per 8x8 block.
// R6: kill accumulator spilling. VGPR_Count=60 across R2-R5 while the
// mandatory live set is ~90 (C[8][8]=64 accumulators + row[8] + tmp[8] +
// addressing) -> compiler's default 8-waves/SIMD VGPR target (~64) forced
// scratch spills every e-iteration. Scratch stays L1/L2-resident (invisible
// in FETCH/WRITE) but eats vector-memory issue slots + latency -- the ~4TB/s
// wall. Grid only supplies 4 waves/SIMD anyway, so the 8-wave target bought
// nothing. __launch_bounds__(64, 4) -> 128-VGPR budget, no spills, still
// full residency for every wave the grid provides.
//
// Input: x (4096 x 4096 fp32). Outputs (concatenated in d_out as float32):
//   [0, 262144)               biggest (512 x 512)
//   [262144, 262144+16777216)  indices as float (512 x 512 x 64)

#define IMG_W 4096
#define NB    512          // blocks per dim
#define NBLK  (NB * NB)    // 262144 total 8x8 blocks
#define WG    64

typedef float f32x4 __attribute__((ext_vector_type(4)));

__global__ __launch_bounds__(WG, 4) void dct_quant_kernel(
    const float* __restrict__ x,
    float* __restrict__ out_big,
    float* __restrict__ out_idx)
{
    // 64 threads x 16 packed u32 (64 int8) each; stride 17 (odd) makes the
    // per-thread column scatter a perfect bank permutation.
    __shared__ unsigned int lds[WG * 17];

    const int t   = threadIdx.x;
    const int bid = blockIdx.x * WG + t;    // 0..NBLK-1
    const int bi  = bid >> 9;               // block row
    const int bj  = bid & (NB - 1);         // block col

    // Orthonormal DCT-II matrix D[e][f] = scale(f) * cos(pi*(2e+1)*f/16),
    // baked as literals so the fully-unrolled loops constant-fold.
    const float s0 = 0.35355339059327373f;   // sqrt(1/8)
    const float d1 = 0.49039264020161522f;
    const float d2 = 0.46193976625564337f;
    const float d3 = 0.41573480615127262f;
    const float d4 = 0.35355339059327379f;
    const float d5 = 0.27778511650980114f;
    const float d6 = 0.19134171618254492f;
    const float d7 = 0.09754516100806413f;

    const float D[8][8] = {
        { s0,  d1,  d2,  d3,  d4,  d5,  d6,  d7},
        { s0,  d3,  d6, -d7, -d4, -d1, -d2, -d5},
        { s0,  d5, -d6, -d1, -d4,  d7,  d2,  d3},
        { s0,  d7, -d2, -d5,  d4,  d3, -d6, -d1},
        { s0, -d7, -d2,  d5,  d4, -d3, -d6,  d1},
        { s0, -d5, -d6,  d1, -d4, -d7,  d2, -d3},
        { s0, -d3,  d6,  d7, -d4,  d1, -d2,  d5},
        { s0, -d1,  d2, -d3,  d4, -d5,  d6, -d7},
    };

    const float* p = x + (size_t)(bi * 8) * IMG_W + (size_t)bj * 8;

    float C[8][8];
#pragma unroll
    for (int g = 0; g < 8; ++g)
#pragma unroll
        for (int h = 0; h < 8; ++h) C[g][h] = 0.0f;

    // C = D^T * X * D, accumulated row-by-row:
    //   tmp[h] = sum_f X[e][f] * D[f][h]   (row transform)
    //   C[g][h] += D[e][g] * tmp[h]        (column transform)
#pragma unroll
    for (int e = 0; e < 8; ++e) {
        const float4 r0 = *reinterpret_cast<const float4*>(p + (size_t)e * IMG_W);
        const float4 r1 = *reinterpret_cast<const float4*>(p + (size_t)e * IMG_W + 4);
        const float row[8] = {r0.x, r0.y, r0.z, r0.w, r1.x, r1.y, r1.z, r1.w};

        float tmp[8];
#pragma unroll
        for (int h = 0; h < 8; ++h) {
            float acc = row[0] * D[0][h];
#pragma unroll
            for (int f = 1; f < 8; ++f) acc = fmaf(row[f], D[f][h], acc);
            tmp[h] = acc;
        }
#pragma unroll
        for (int g = 0; g < 8; ++g) {
#pragma unroll
            for (int h = 0; h < 8; ++h) C[g][h] = fmaf(D[e][g], tmp[h], C[g][h]);
        }
    }

    // Per-block abs-max
    float big = 0.0f;
#pragma unroll
    for (int g = 0; g < 8; ++g)
#pragma unroll
        for (int h = 0; h < 8; ++h) big = fmaxf(big, fabsf(C[g][h]));

    __builtin_nontemporal_store(big, &out_big[bid]);  // coalesced, nt

    const float safe = (big == 0.0f) ? 1.0f : big;
    const float inv  = 127.0f / safe;

    // Quantize to int8, pack 4 per u32, stage in LDS.
#pragma unroll
    for (int g = 0; g < 8; ++g) {
        int q[8];
#pragma unroll
        for (int h = 0; h < 8; ++h) q[h] = (int)rintf(C[g][h] * inv);  // [-127,127]
        const unsigned int w0 = (q[0] & 0xff) | ((q[1] & 0xff) << 8) |
                                ((q[2] & 0xff) << 16) | ((unsigned)(q[3] & 0xff) << 24);
        const unsigned int w1 = (q[4] & 0xff) | ((q[5] & 0xff) << 8) |
                                ((q[6] & 0xff) << 16) | ((unsigned)(q[7] & 0xff) << 24);
        lds[t * 17 + 2 * g]     = w0;
        lds[t * 17 + 2 * g + 1] = w1;
    }

    __syncthreads();   // single-wave WG: compiles to lgkmcnt wait, no s_barrier

    // Coalesced copy-out: 1024 float4s per WG; each float4 unpacks one u32.
    f32x4* og = reinterpret_cast<f32x4*>(out_idx) + (size_t)blockIdx.x * 1024;
#pragma unroll
    for (int k = 0; k < 16; ++k) {
        const int F = k * WG + t;           // flat u32 index in this WG's region
        const unsigned int w = lds[(F >> 4) * 17 + (F & 15)];
        f32x4 q;
        q.x = (float)(int)(signed char)(w       & 0xff);
        q.y = (float)(int)(signed char)((w >> 8)  & 0xff);
        q.z = (float)(int)(signed char)((w >> 16) & 0xff);
        q.w = (float)(int)(signed char)(w >> 24);
        __builtin_nontemporal_store(q, &og[F]);
    }
}

extern "C" void kernel_launch(void* const* d_in, const int* in_sizes, int n_in,
                              void* d_out, int out_size, void* d_ws, size_t ws_size,
                              hipStream_t stream) {
    const float* x = (const float*)d_in[0];
    float* out = (float*)d_out;
    float* out_big = out;          // 262144 floats
    float* out_idx = out + NBLK;   // 16777216 floats

    dct_quant_kernel<<<NBLK / WG, WG, 0, stream>>>(x, out_big, out_idx);
}

// Round 8
// 25.293 us; speedup vs baseline: 1.0224x; 1.0224x over previous
//
#include <hip/hip_runtime.h>

// PyBlaz 8x8 block DCT + int8 quantization.
// R7 restructure: 8 lanes cooperate per 8x8 block (one lane per row).
//   - R0-R6 all had one thread per block: C[8][8]+row+tmp ~= 90 live values
//     vs VGPR_Count=60, long serial chains, only 16 waves/CU. Four
//     single-variable fixes (occupancy, barrier, nt, reg budget) all
//     landed at ~4 TB/s while the harness fill kernel does 6.5 TB/s.
//   - Now: lane (b,e) loads row e of block b (32B), row-transforms in
//     registers, XOR-swizzled LDS transpose, column-transforms with a
//     per-lane D-column built once via v_cos_f32. ~35 live values, short
//     chains, 32 waves/CU.
//
// Input: x (4096 x 4096 fp32). Outputs (concatenated in d_out as float32):
//   [0, 262144)               biggest (512 x 512)
//   [262144, 262144+16777216)  indices as float (512 x 512 x 64)

#define IMG_W 4096
#define NB    512          // blocks per dim
#define NBLK  (NB * NB)    // 262144 total 8x8 blocks
#define WG    64           // one wave; handles 8 consecutive blocks

typedef float f32x4 __attribute__((ext_vector_type(4)));

__global__ __launch_bounds__(WG) void dct_quant_kernel(
    const float* __restrict__ x,
    float* __restrict__ out_big,
    float* __restrict__ out_idx)
{
    // Transpose buffer: 8 blocks, stride 72 dwords (8x8 + 8 pad) so the
    // (b,e) write pattern is a 2-way bank alias (free, m136).
    __shared__ __align__(16) float T[8 * 72];     // 2304 B
    __shared__ float Dl[64];                       // D[e][f] table, 256 B
    __shared__ unsigned int Sg[8 * 18];            // packed staging, 576 B

    const int l = threadIdx.x;
    const int b = l & 7;       // block-within-wave
    const int g = l >> 3;      // row index: phase1 'e' role, phase2 'g' role

    // ---- Build D table: lane l computes D[e'][f'], (e',f') = (g, b) ----
    // D[e][f] = scale(f) * cos(pi*(2e+1)*f/16); revolutions = (2e+1)*f/32.
    {
        float rev = (float)((2 * g + 1) * b) * (1.0f / 32.0f);
        rev = rev - floorf(rev);                   // v_fract
        float c;
        asm("v_cos_f32 %0, %1" : "=v"(c) : "v"(rev));  // input in revolutions
        const float sc = (b == 0) ? 0.35355339059327373f : 0.5f;
        Dl[g * 8 + b] = sc * c;                    // Dl[e'*8+f']
    }

    const int gblk0 = blockIdx.x * 8;              // 8 consecutive blocks
    const int gblk  = gblk0 + b;
    const int bi = gblk >> 9;                      // uniform across the wave
    const int bj = gblk & (NB - 1);

    // ---- Phase 1: load row 'g' of block b, row transform, swizzled store ----
    // Compile-time D literals for the row transform.
    const float s0 = 0.35355339059327373f;
    const float d1 = 0.49039264020161522f;
    const float d2 = 0.46193976625564337f;
    const float d3 = 0.41573480615127262f;
    const float d4 = 0.35355339059327379f;
    const float d5 = 0.27778511650980114f;
    const float d6 = 0.19134171618254492f;
    const float d7 = 0.09754516100806413f;
    const float D[8][8] = {
        { s0,  d1,  d2,  d3,  d4,  d5,  d6,  d7},
        { s0,  d3,  d6, -d7, -d4, -d1, -d2, -d5},
        { s0,  d5, -d6, -d1, -d4,  d7,  d2,  d3},
        { s0,  d7, -d2, -d5,  d4,  d3, -d6, -d1},
        { s0, -d7, -d2,  d5,  d4, -d3, -d6,  d1},
        { s0, -d5, -d6,  d1, -d4, -d7,  d2, -d3},
        { s0, -d3,  d6,  d7, -d4,  d1, -d2,  d5},
        { s0, -d1,  d2, -d3,  d4, -d5,  d6, -d7},
    };

    const float* p = x + (size_t)(bi * 8 + g) * IMG_W + (size_t)bj * 8;
    const float4 r0 = *reinterpret_cast<const float4*>(p);
    const float4 r1 = *reinterpret_cast<const float4*>(p + 4);
    const float row[8] = {r0.x, r0.y, r0.z, r0.w, r1.x, r1.y, r1.z, r1.w};

    // tmp[h] = sum_f row[f] * D[f][h]; store swizzled: T[b*72 + e*8 + (h^e)]
    float* tw = &T[b * 72 + g * 8];
#pragma unroll
    for (int h = 0; h < 8; ++h) {
        float acc = row[0] * D[0][h];
#pragma unroll
        for (int f = 1; f < 8; ++f) acc = fmaf(row[f], D[f][h], acc);
        tw[h ^ g] = acc;
    }

    __syncthreads();   // single-wave WG: lgkmcnt-only

    // ---- Phase 2: column transform. Lane (b,g) computes C[g][0..7]. ----
    float Dg[8];
#pragma unroll
    for (int e = 0; e < 8; ++e) Dg[e] = Dl[e * 8 + g];  // broadcast reads

    float C[8];
#pragma unroll
    for (int h = 0; h < 8; ++h) C[h] = 0.0f;

    const float* tr = &T[b * 72];
#pragma unroll
    for (int e = 0; e < 8; ++e) {
        // 8 dwords at tr + e*8 (16B-aligned): rj[j] = tmp_e[j^e]
        const float4 a0 = *reinterpret_cast<const float4*>(tr + e * 8);
        const float4 a1 = *reinterpret_cast<const float4*>(tr + e * 8 + 4);
        const float rj[8] = {a0.x, a0.y, a0.z, a0.w, a1.x, a1.y, a1.z, a1.w};
#pragma unroll
        for (int h = 0; h < 8; ++h)
            C[h] = fmaf(Dg[e], rj[h ^ e], C[h]);   // tmp_e[h] = rj[h^e]
    }

    // ---- abs-max across this lane's 8 values, then across the 8 g-lanes ----
    float m = fabsf(C[0]);
#pragma unroll
    for (int h = 1; h < 8; ++h) m = fmaxf(m, fabsf(C[h]));
    m = fmaxf(m, __shfl_xor(m, 8, 64));
    m = fmaxf(m, __shfl_xor(m, 16, 64));
    m = fmaxf(m, __shfl_xor(m, 32, 64));   // all lanes of block b now hold max

    if (g == 0)    // lanes 0..7 -> 8 consecutive dwords
        __builtin_nontemporal_store(m, &out_big[gblk0 + b]);

    const float safe = (m == 0.0f) ? 1.0f : m;
    const float inv  = 127.0f / safe;

    // ---- Quantize, pack 8 int8 -> 2 u32, stage ----
    int q[8];
#pragma unroll
    for (int h = 0; h < 8; ++h) q[h] = (int)rintf(C[h] * inv);
    const unsigned int w0 = (q[0] & 0xff) | ((q[1] & 0xff) << 8) |
                            ((q[2] & 0xff) << 16) | ((unsigned)(q[3] & 0xff) << 24);
    const unsigned int w1 = (q[4] & 0xff) | ((q[5] & 0xff) << 8) |
                            ((q[6] & 0xff) << 16) | ((unsigned)(q[7] & 0xff) << 24);
    Sg[b * 18 + g * 2]     = w0;
    Sg[b * 18 + g * 2 + 1] = w1;

    __syncthreads();

    // ---- Dense copy-out: 8 blocks x 256 B = 2 KB contiguous per wave ----
    // 128 float4s; lane l writes float4 #l and #(l+64); float4 #k unpacks
    // packed u32 #k = Sg[(k>>4)*18 + (k&15)].
    f32x4* og = reinterpret_cast<f32x4*>(out_idx + (size_t)gblk0 * 64);
#pragma unroll
    for (int kk = 0; kk < 2; ++kk) {
        const int k = kk * 64 + l;
        const unsigned int w = Sg[(k >> 4) * 18 + (k & 15)];
        f32x4 qv;
        qv.x = (float)(int)(signed char)(w        & 0xff);
        qv.y = (float)(int)(signed char)((w >> 8)  & 0xff);
        qv.z = (float)(int)(signed char)((w >> 16) & 0xff);
        qv.w = (float)(int)(signed char)(w >> 24);
        __builtin_nontemporal_store(qv, &og[k]);
    }
}

extern "C" void kernel_launch(void* const* d_in, const int* in_sizes, int n_in,
                              void* d_out, int out_size, void* d_ws, size_t ws_size,
                              hipStream_t stream) {
    const float* x = (const float*)d_in[0];
    float* out = (float*)d_out;
    float* out_big = out;          // 262144 floats
    float* out_idx = out + NBLK;   // 16777216 floats

    dct_quant_kernel<<<NBLK / 8, WG, 0, stream>>>(x, out_big, out_idx);
}